// Round 16
// baseline (85.327 us; speedup 1.0000x reference)
//
#include <hip/hip_runtime.h>
#include <stdint.h>

#define B_ 64
#define T_ 256
#define DF 32
#define L_ 128
#define AW 34      // solve-matrix row stride in floats
#define SLICE 4352 // one token's solve matrix: 32*34*4

typedef float  v2f    __attribute__((ext_vector_type(2)));
typedef float  f32x16 __attribute__((ext_vector_type(16)));
typedef short  bf16x8 __attribute__((ext_vector_type(8)));

// wave-private barrier: drain LDS ops; sched_barrier stops hoisting (rule #18)
#define WAVE_SYNC() do { asm volatile("s_waitcnt lgkmcnt(0)" ::: "memory"); \
                         __builtin_amdgcn_sched_barrier(0); } while (0)

__device__ __forceinline__ float readlane_f(float v, int l) {
    return __builtin_bit_cast(float, __builtin_amdgcn_readlane(__builtin_bit_cast(int, v), l));
}
__device__ __forceinline__ v2f pk_fma(v2f a, v2f b, v2f c) {
    v2f d;
    asm("v_pk_fma_f32 %0, %1, %2, %3" : "=v"(d) : "v"(a), "v"(b), "v"(c));
    return d;
}
__device__ __forceinline__ uint32_t cvt_pk_bf16(float a, float b) {
    uint32_t r;
    asm("v_cvt_pk_bf16_f32 %0, %1, %2" : "=v"(r) : "v"(a), "v"(b));
    return r;   // lo16 = bf16(a), hi16 = bf16(b)
}
__device__ __forceinline__ float lo_f(uint32_t p) { return __builtin_bit_cast(float, p << 16); }
__device__ __forceinline__ float hi_f(uint32_t p) { return __builtin_bit_cast(float, p & 0xFFFF0000u); }

struct frag2m { bf16x8 h, m; };
union U8 { uint32_t u[4]; bf16x8 v; };

// 2-way bf16 split of 8 f32 values (four v2f): f ~= h + m, residual ~2^-18
__device__ __forceinline__ frag2m split2(v2f p0, v2f p1, v2f p2, v2f p3) {
    uint32_t h0 = cvt_pk_bf16(p0[0], p0[1]), h1 = cvt_pk_bf16(p1[0], p1[1]);
    uint32_t h2 = cvt_pk_bf16(p2[0], p2[1]), h3 = cvt_pk_bf16(p3[0], p3[1]);
    float e0 = p0[0] - lo_f(h0), e1 = p0[1] - hi_f(h0);
    float e2 = p1[0] - lo_f(h1), e3 = p1[1] - hi_f(h1);
    float e4 = p2[0] - lo_f(h2), e5 = p2[1] - hi_f(h2);
    float e6 = p3[0] - lo_f(h3), e7 = p3[1] - hi_f(h3);
    uint32_t m0 = cvt_pk_bf16(e0, e1), m1 = cvt_pk_bf16(e2, e3);
    uint32_t m2 = cvt_pk_bf16(e4, e5), m3 = cvt_pk_bf16(e6, e7);
    U8 H, M;
    H.u[0] = h0; H.u[1] = h1; H.u[2] = h2; H.u[3] = h3;
    M.u[0] = m0; M.u[1] = m1; M.u[2] = m2; M.u[3] = m3;
    frag2m r; r.h = H.v; r.m = M.v; return r;
}

__device__ __forceinline__ f32x16 mfma32(bf16x8 a, bf16x8 b, f32x16 c) {
    return __builtin_amdgcn_mfma_f32_32x32x16_bf16(a, b, c, 0, 0, 0);
}

// ---- merged Gauss-Jordan round K, VALU broadcast (no DS ops) ----
// lane g*32+r holds FULL row r (33 floats) of token g.
// Broadcast row K via 2x v_readlane (SGPR) + 2 chained fma with half-masked
// multipliers: lanes of the other half add fma(-0, pk, A[m]) = A[m].
template <int K>
__device__ __forceinline__ void gj_round(float (&A)[33], float& dinv, int r, int g) {
    float pivA = readlane_f(A[K], K);        // token A's A[K][K] (SGPR)
    float pivB = readlane_f(A[K], 32 + K);   // token B's A[K][K] (SGPR)
    float piv  = g ? pivB : pivA;
    float ip = __builtin_amdgcn_rcpf(piv);   // ~1 ulp native rcp
    const bool isk = (r == K);
    float fmul = isk ? 0.f : A[K] * ip;      // my row's col-K value (in reg)
    dinv = isk ? ip : dinv;                  // capture my diagonal reciprocal
    float fA = g ? 0.f : fmul;               // half-masked multipliers
    float fB = g ? fmul : 0.f;
    #pragma unroll
    for (int m = K + 1; m < 33; ++m) {
        float pkA = readlane_f(A[m], K);      // row K col m, token A (SGPR)
        float pkB = readlane_f(A[m], 32 + K); // row K col m, token B (SGPR)
        A[m] = fmaf(-fA, pkA, A[m]);
        A[m] = fmaf(-fB, pkB, A[m]);
    }
}

template <int K>
struct GJ {
    static __device__ __forceinline__ void run(float (&A)[33], float& dinv, int r, int g) {
        gj_round<K>(A, dinv, r, g);
        GJ<K + 1>::run(A, dinv, r, g);
    }
};
template <>
struct GJ<32> {
    static __device__ __forceinline__ void run(float (&)[33], float&, int, int) {}
};

// 256-thread blocks = 4 independent waves (no __syncthreads); each wave: 2 tokens.
__global__ __launch_bounds__(256, 4) void feat_kernel(
    const float* __restrict__ x,       // [B,T,32]
    const float* __restrict__ latent,  // [B,T,128]
    const float* __restrict__ kern,    // [32,128]
    const float* __restrict__ bias,    // [32,128]
    const float* __restrict__ beta,    // [T]
    float* __restrict__ out,           // mode0: ws[B,T,128] ; mode1: out[B,128]
    int mode)
{
    __shared__ __align__(16) char smem[8 * SLICE];
    const int tid  = threadIdx.x;
    const int wid  = tid >> 6;         // wave within block (0..3)
    const int lane = tid & 63;
    const int btA  = blockIdx.x * 8 + wid * 2;
    const int btB  = btA + 1;

    const int g = lane >> 5;
    const int r = lane & 31;

    float* AsA = reinterpret_cast<float*>(smem + (wid * 2 + 0) * SLICE);
    float* AsB = reinterpret_cast<float*>(smem + (wid * 2 + 1) * SLICE);

    const float4* kern4 = reinterpret_cast<const float4*>(kern);
    const float4* bias4 = reinterpret_cast<const float4*>(bias);
    const float4* latA4 = reinterpret_cast<const float4*>(latent) + (size_t)btA * 32;
    const float4* latB4 = reinterpret_cast<const float4*>(latent) + (size_t)btB * 32;

    const float xA = x[(size_t)btA * DF + r];   // x_A[r] in every lane (both halves)
    const float xB = x[(size_t)btB * DF + r];
    const v2f xA2 = {xA, xA}, xB2 = {xB, xB};

    f32x16 GA, GB;
    #pragma unroll
    for (int i = 0; i < 16; ++i) { GA[i] = 0.f; GB[i] = 0.f; }
    v2f ayA2 = {0.f, 0.f}, ayB2 = {0.f, 0.f};

    // ---- 8 k-steps of 16: shared K/B loads, both tokens' frags, 8 MFMA/ks ----
    #pragma unroll 2
    for (int ks = 0; ks < 8; ++ks) {
        const int idx = r * 32 + ks * 4 + g * 2;   // float4 index; k = ks*16 + g*8
        float4 Ka = kern4[idx],  Kb = kern4[idx + 1];
        float4 Ba = bias4[idx],  Bb = bias4[idx + 1];
        v2f K0 = {Ka.x, Ka.y}, K1 = {Ka.z, Ka.w};
        v2f K2 = {Kb.x, Kb.y}, K3 = {Kb.z, Kb.w};
        v2f B0 = {Ba.x, Ba.y}, B1 = {Ba.z, Ba.w};
        v2f B2 = {Bb.x, Bb.y}, B3 = {Bb.z, Bb.w};

        // token A features (pk fma + scalar relu)
        v2f a0 = pk_fma(xA2, K0, B0), a1 = pk_fma(xA2, K1, B1);
        v2f a2 = pk_fma(xA2, K2, B2), a3 = pk_fma(xA2, K3, B3);
        a0[0] = fmaxf(a0[0], 0.f); a0[1] = fmaxf(a0[1], 0.f);
        a1[0] = fmaxf(a1[0], 0.f); a1[1] = fmaxf(a1[1], 0.f);
        a2[0] = fmaxf(a2[0], 0.f); a2[1] = fmaxf(a2[1], 0.f);
        a3[0] = fmaxf(a3[0], 0.f); a3[1] = fmaxf(a3[1], 0.f);
        // token B features
        v2f b0 = pk_fma(xB2, K0, B0), b1 = pk_fma(xB2, K1, B1);
        v2f b2 = pk_fma(xB2, K2, B2), b3 = pk_fma(xB2, K3, B3);
        b0[0] = fmaxf(b0[0], 0.f); b0[1] = fmaxf(b0[1], 0.f);
        b1[0] = fmaxf(b1[0], 0.f); b1[1] = fmaxf(b1[1], 0.f);
        b2[0] = fmaxf(b2[0], 0.f); b2[1] = fmaxf(b2[1], 0.f);
        b3[0] = fmaxf(b3[0], 0.f); b3[1] = fmaxf(b3[1], 0.f);

        // xty partials (pk f32, exact)
        float4 laA = latA4[ks * 4 + g * 2], lbA = latA4[ks * 4 + g * 2 + 1];
        float4 laB = latB4[ks * 4 + g * 2], lbB = latB4[ks * 4 + g * 2 + 1];
        v2f lA0 = {laA.x, laA.y}, lA1 = {laA.z, laA.w};
        v2f lA2 = {lbA.x, lbA.y}, lA3 = {lbA.z, lbA.w};
        v2f lB0 = {laB.x, laB.y}, lB1 = {laB.z, laB.w};
        v2f lB2 = {lbB.x, lbB.y}, lB3 = {lbB.z, lbB.w};
        ayA2 = pk_fma(a0, lA0, ayA2); ayA2 = pk_fma(a1, lA1, ayA2);
        ayA2 = pk_fma(a2, lA2, ayA2); ayA2 = pk_fma(a3, lA3, ayA2);
        ayB2 = pk_fma(b0, lB0, ayB2); ayB2 = pk_fma(b1, lB1, ayB2);
        ayB2 = pk_fma(b2, lB2, ayB2); ayB2 = pk_fma(b3, lB3, ayB2);

        frag2m FA = split2(a0, a1, a2, a3);
        frag2m FB = split2(b0, b1, b2, b3);
        // G += (h+m)(h+m)^T exactly: hh + hm + mh + mm  (residual ~2^-17 rel)
        GA = mfma32(FA.h, FA.h, GA);
        GB = mfma32(FB.h, FB.h, GB);
        GA = mfma32(FA.h, FA.m, GA);
        GB = mfma32(FB.h, FB.m, GB);
        GA = mfma32(FA.m, FA.h, GA);
        GB = mfma32(FB.m, FB.h, GB);
        GA = mfma32(FA.m, FA.m, GA);
        GB = mfma32(FB.m, FB.m, GB);
    }
    float ayA = ayA2[0] + ayA2[1];
    float ayB = ayB2[0] + ayB2[1];
    ayA += __shfl_xor(ayA, 32);   // full xty_A[r] in every lane
    ayB += __shfl_xor(ayB, 32);

    // ---- spill both Grams + xty into LDS (row-major, m101 C-layout) ----
    #pragma unroll
    for (int reg = 0; reg < 16; ++reg) {
        const int row = (reg & 3) + 8 * (reg >> 2) + 4 * g;
        AsA[row * AW + r] = GA[reg];
        AsB[row * AW + r] = GB[reg];
    }
    if (g == 0) AsA[r * AW + 32] = ayA;
    else        AsB[r * AW + 32] = ayB;
    WAVE_SYNC();

    // ---- reload: lane g*32+r <- FULL row r of token g ----
    float A[33];
    {
        const float* Amy = g ? AsB : AsA;
        #pragma unroll
        for (int m = 0; m < 16; ++m) {
            v2f t = *reinterpret_cast<const v2f*>(&Amy[r * AW + 2 * m]);
            A[2 * m]     = t[0];
            A[2 * m + 1] = t[1];
        }
        A[32] = Amy[r * AW + 32];
    }

    // ---- merged register Gauss-Jordan: VALU broadcasts, zero DS ops ----
    float dinv = 0.f;
    GJ<0>::run(A, dinv, r, g);
    const float s = A[32] * dinv;   // lane g*32+r: solution s_g[r]

    // ---- o_hat both tokens: shared K/Bv loads, f4-col = r, d split across halves ----
    {
        v2f oA01 = {0.f, 0.f}, oA23 = {0.f, 0.f};
        v2f oB01 = {0.f, 0.f}, oB23 = {0.f, 0.f};
        #pragma unroll
        for (int dd = 0; dd < 16; ++dd) {
            int d = g * 16 + dd;
            float4 K  = kern4[d * 32 + r];
            float4 Bv = bias4[d * 32 + r];
            v2f K01 = {K.x, K.y},  K23 = {K.z, K.w};
            v2f Bv01 = {Bv.x, Bv.y}, Bv23 = {Bv.z, Bv.w};
            float xvA = __shfl(xA, d);        // x_A[d]
            float xvB = __shfl(xB, d);
            v2f xvA2 = {xvA, xvA}, xvB2 = {xvB, xvB};
            float sA = __shfl(s, d);          // s_A[d] (from half 0)
            float sB = __shfl(s, 32 + d);     // s_B[d] (from half 1)
            v2f sA2 = {sA, sA}, sB2 = {sB, sB};
            v2f f01 = pk_fma(xvA2, K01, Bv01);
            v2f f23 = pk_fma(xvA2, K23, Bv23);
            f01[0] = fmaxf(f01[0], 0.f); f01[1] = fmaxf(f01[1], 0.f);
            f23[0] = fmaxf(f23[0], 0.f); f23[1] = fmaxf(f23[1], 0.f);
            oA01 = pk_fma(sA2, f01, oA01);
            oA23 = pk_fma(sA2, f23, oA23);
            f01 = pk_fma(xvB2, K01, Bv01);
            f23 = pk_fma(xvB2, K23, Bv23);
            f01[0] = fmaxf(f01[0], 0.f); f01[1] = fmaxf(f01[1], 0.f);
            f23[0] = fmaxf(f23[0], 0.f); f23[1] = fmaxf(f23[1], 0.f);
            oB01 = pk_fma(sB2, f01, oB01);
            oB23 = pk_fma(sB2, f23, oB23);
        }
        float4 oA = make_float4(oA01[0], oA01[1], oA23[0], oA23[1]);
        float4 oB = make_float4(oB01[0], oB01[1], oB23[0], oB23[1]);
        oA.x += __shfl_xor(oA.x, 32); oA.y += __shfl_xor(oA.y, 32);
        oA.z += __shfl_xor(oA.z, 32); oA.w += __shfl_xor(oA.w, 32);
        oB.x += __shfl_xor(oB.x, 32); oB.y += __shfl_xor(oB.y, 32);
        oB.z += __shfl_xor(oB.z, 32); oB.w += __shfl_xor(oB.w, 32);

        if (mode == 0) {
            if (g == 0) reinterpret_cast<float4*>(out)[(size_t)btA * 32 + r] = oA;
            else        reinterpret_cast<float4*>(out)[(size_t)btB * 32 + r] = oB;
        } else {
            float v = fabsf(beta[lane]) + fabsf(beta[lane + 64]) +
                      fabsf(beta[lane + 128]) + fabsf(beta[lane + 192]);
            #pragma unroll
            for (int off = 32; off > 0; off >>= 1) v += __shfl_down(v, off);
            float S = __shfl(v, 0);
            const int tA = btA & (T_ - 1), tB = btB & (T_ - 1);
            const int b  = btA >> 8;
            float* op = &out[(size_t)b * L_ + 4 * r];
            if (g == 0) {
                float w_t = fabsf(beta[tA]) / S;
                atomicAdd(op + 0, oA.x * w_t);
                atomicAdd(op + 1, oA.y * w_t);
                atomicAdd(op + 2, oA.z * w_t);
                atomicAdd(op + 3, oA.w * w_t);
            } else {
                float w_t = fabsf(beta[tB]) / S;
                atomicAdd(op + 0, oB.x * w_t);
                atomicAdd(op + 1, oB.y * w_t);
                atomicAdd(op + 2, oB.z * w_t);
                atomicAdd(op + 3, oB.w * w_t);
            }
        }
    }
}

__global__ __launch_bounds__(256) void reduce_kernel(
    const float* __restrict__ ws,     // [B,T,128] o_hat (unscaled)
    const float* __restrict__ beta,   // [T]
    float* __restrict__ out)          // [B,128]
{
    __shared__ float wsh[T_];
    __shared__ __align__(16) float4 par[8][32];
    __shared__ float red[4];
    const int b = blockIdx.x, tid = threadIdx.x;

    float bv = fabsf(beta[tid]);
    wsh[tid] = bv;
    float v = bv;
    #pragma unroll
    for (int o = 32; o > 0; o >>= 1) v += __shfl_down(v, o);
    if ((tid & 63) == 0) red[tid >> 6] = v;
    __syncthreads();
    const float S = red[0] + red[1] + red[2] + red[3];

    const int c = tid & 31, gg = tid >> 5;
    const float4* ws4 = reinterpret_cast<const float4*>(ws);
    float4 a = make_float4(0.f, 0.f, 0.f, 0.f);
    #pragma unroll 4
    for (int tt = 0; tt < 32; ++tt) {
        int t = gg * 32 + tt;
        float w = wsh[t];
        float4 u = ws4[((size_t)b * T_ + t) * 32 + c];
        a.x = fmaf(u.x, w, a.x);
        a.y = fmaf(u.y, w, a.y);
        a.z = fmaf(u.z, w, a.z);
        a.w = fmaf(u.w, w, a.w);
    }
    par[gg][c] = a;
    __syncthreads();
    if (tid < 32) {
        float4 s = par[0][tid];
        #pragma unroll
        for (int p = 1; p < 8; ++p) {
            float4 u = par[p][tid];
            s.x += u.x; s.y += u.y; s.z += u.z; s.w += u.w;
        }
        float inv = 1.0f / S;
        s.x *= inv; s.y *= inv; s.z *= inv; s.w *= inv;
        reinterpret_cast<float4*>(out)[b * 32 + tid] = s;
    }
}

extern "C" void kernel_launch(void* const* d_in, const int* in_sizes, int n_in,
                              void* d_out, int out_size, void* d_ws, size_t ws_size,
                              hipStream_t stream) {
    const float* x      = (const float*)d_in[0];
    const float* latent = (const float*)d_in[1];
    const float* kern   = (const float*)d_in[2];
    const float* bias   = (const float*)d_in[3];
    const float* beta   = (const float*)d_in[4];
    float* out = (float*)d_out;

    const size_t need = (size_t)B_ * T_ * L_ * sizeof(float);
    if (ws_size >= need) {
        float* ws = (float*)d_ws;
        feat_kernel<<<(B_ * T_) / 8, 256, 0, stream>>>(x, latent, kern, bias, beta, ws, 0);
        reduce_kernel<<<B_, 256, 0, stream>>>(ws, beta, out);
    } else {
        (void)hipMemsetAsync(d_out, 0, (size_t)out_size * sizeof(float), stream);
        feat_kernel<<<(B_ * T_) / 8, 256, 0, stream>>>(x, latent, kern, bias, beta, out, 1);
    }
}

// Round 17
// 78.237 us; speedup vs baseline: 1.0906x; 1.0906x over previous
//
#include <hip/hip_runtime.h>
#include <stdint.h>

#define B_ 64
#define T_ 256
#define DF 32
#define L_ 128
#define AW 34      // solve-matrix row stride in floats
#define SLICE 4352 // one token's solve matrix: 32*34*4

typedef float  v2f    __attribute__((ext_vector_type(2)));
typedef float  f32x16 __attribute__((ext_vector_type(16)));
typedef short  bf16x8 __attribute__((ext_vector_type(8)));

// wave-private barrier: drain LDS ops; sched_barrier stops hoisting (rule #18)
#define WAVE_SYNC() do { asm volatile("s_waitcnt lgkmcnt(0)" ::: "memory"); \
                         __builtin_amdgcn_sched_barrier(0); } while (0)

// ds_swizzle with compile-time immediate (builtin requires an ICE argument)
template <int IMM>
__device__ __forceinline__ float swz_f(float v) {
    return __builtin_bit_cast(float, __builtin_amdgcn_ds_swizzle(
        __builtin_bit_cast(int, v), IMM));
}
__device__ __forceinline__ v2f pk_fma(v2f a, v2f b, v2f c) {
    v2f d;
    asm("v_pk_fma_f32 %0, %1, %2, %3" : "=v"(d) : "v"(a), "v"(b), "v"(c));
    return d;
}
__device__ __forceinline__ uint32_t cvt_pk_bf16(float a, float b) {
    uint32_t r;
    asm("v_cvt_pk_bf16_f32 %0, %1, %2" : "=v"(r) : "v"(a), "v"(b));
    return r;   // lo16 = bf16(a), hi16 = bf16(b)
}
__device__ __forceinline__ float lo_f(uint32_t p) { return __builtin_bit_cast(float, p << 16); }
__device__ __forceinline__ float hi_f(uint32_t p) { return __builtin_bit_cast(float, p & 0xFFFF0000u); }

struct frag2m { bf16x8 h, m; };
union U8 { uint32_t u[4]; bf16x8 v; };

// 2-way bf16 split of 8 f32 values (four v2f): f ~= h + m, residual ~2^-18
__device__ __forceinline__ frag2m split2(v2f p0, v2f p1, v2f p2, v2f p3) {
    uint32_t h0 = cvt_pk_bf16(p0[0], p0[1]), h1 = cvt_pk_bf16(p1[0], p1[1]);
    uint32_t h2 = cvt_pk_bf16(p2[0], p2[1]), h3 = cvt_pk_bf16(p3[0], p3[1]);
    float e0 = p0[0] - lo_f(h0), e1 = p0[1] - hi_f(h0);
    float e2 = p1[0] - lo_f(h1), e3 = p1[1] - hi_f(h1);
    float e4 = p2[0] - lo_f(h2), e5 = p2[1] - hi_f(h2);
    float e6 = p3[0] - lo_f(h3), e7 = p3[1] - hi_f(h3);
    uint32_t m0 = cvt_pk_bf16(e0, e1), m1 = cvt_pk_bf16(e2, e3);
    uint32_t m2 = cvt_pk_bf16(e4, e5), m3 = cvt_pk_bf16(e6, e7);
    U8 H, M;
    H.u[0] = h0; H.u[1] = h1; H.u[2] = h2; H.u[3] = h3;
    M.u[0] = m0; M.u[1] = m1; M.u[2] = m2; M.u[3] = m3;
    frag2m r; r.h = H.v; r.m = M.v; return r;
}

__device__ __forceinline__ f32x16 mfma32(bf16x8 a, bf16x8 b, f32x16 c) {
    return __builtin_amdgcn_mfma_f32_32x32x16_bf16(a, b, c, 0, 0, 0);
}

// ---- one Gram k-step (16 k-elems) for a token pair X,Y ----
__device__ __forceinline__ void gram_ks(
    int ks, const float4* __restrict__ kern4, const float4* __restrict__ bias4,
    const float4* __restrict__ latX4, const float4* __restrict__ latY4,
    float xX, float xY, int r, int g,
    f32x16& GX, f32x16& GY, v2f& ayX2, v2f& ayY2)
{
    const v2f xX2 = {xX, xX}, xY2 = {xY, xY};
    const int idx = r * 32 + ks * 4 + g * 2;   // float4 index; k = ks*16 + g*8
    float4 Ka = kern4[idx],  Kb = kern4[idx + 1];
    float4 Ba = bias4[idx],  Bb = bias4[idx + 1];
    v2f K0 = {Ka.x, Ka.y}, K1 = {Ka.z, Ka.w};
    v2f K2 = {Kb.x, Kb.y}, K3 = {Kb.z, Kb.w};
    v2f B0 = {Ba.x, Ba.y}, B1 = {Ba.z, Ba.w};
    v2f B2 = {Bb.x, Bb.y}, B3 = {Bb.z, Bb.w};

    v2f a0 = pk_fma(xX2, K0, B0), a1 = pk_fma(xX2, K1, B1);
    v2f a2 = pk_fma(xX2, K2, B2), a3 = pk_fma(xX2, K3, B3);
    a0[0] = fmaxf(a0[0], 0.f); a0[1] = fmaxf(a0[1], 0.f);
    a1[0] = fmaxf(a1[0], 0.f); a1[1] = fmaxf(a1[1], 0.f);
    a2[0] = fmaxf(a2[0], 0.f); a2[1] = fmaxf(a2[1], 0.f);
    a3[0] = fmaxf(a3[0], 0.f); a3[1] = fmaxf(a3[1], 0.f);
    v2f b0 = pk_fma(xY2, K0, B0), b1 = pk_fma(xY2, K1, B1);
    v2f b2 = pk_fma(xY2, K2, B2), b3 = pk_fma(xY2, K3, B3);
    b0[0] = fmaxf(b0[0], 0.f); b0[1] = fmaxf(b0[1], 0.f);
    b1[0] = fmaxf(b1[0], 0.f); b1[1] = fmaxf(b1[1], 0.f);
    b2[0] = fmaxf(b2[0], 0.f); b2[1] = fmaxf(b2[1], 0.f);
    b3[0] = fmaxf(b3[0], 0.f); b3[1] = fmaxf(b3[1], 0.f);

    float4 laX = latX4[ks * 4 + g * 2], lbX = latX4[ks * 4 + g * 2 + 1];
    float4 laY = latY4[ks * 4 + g * 2], lbY = latY4[ks * 4 + g * 2 + 1];
    v2f lX0 = {laX.x, laX.y}, lX1 = {laX.z, laX.w};
    v2f lX2 = {lbX.x, lbX.y}, lX3 = {lbX.z, lbX.w};
    v2f lY0 = {laY.x, laY.y}, lY1 = {laY.z, laY.w};
    v2f lY2 = {lbY.x, lbY.y}, lY3 = {lbY.z, lbY.w};
    ayX2 = pk_fma(a0, lX0, ayX2); ayX2 = pk_fma(a1, lX1, ayX2);
    ayX2 = pk_fma(a2, lX2, ayX2); ayX2 = pk_fma(a3, lX3, ayX2);
    ayY2 = pk_fma(b0, lY0, ayY2); ayY2 = pk_fma(b1, lY1, ayY2);
    ayY2 = pk_fma(b2, lY2, ayY2); ayY2 = pk_fma(b3, lY3, ayY2);

    frag2m FX = split2(a0, a1, a2, a3);
    frag2m FY = split2(b0, b1, b2, b3);
    GX = mfma32(FX.h, FX.h, GX);
    GY = mfma32(FY.h, FY.h, GY);
    GX = mfma32(FX.h, FX.m, GX);
    GY = mfma32(FY.h, FY.m, GY);
    GX = mfma32(FX.m, FX.h, GX);
    GY = mfma32(FY.m, FY.h, GY);
    GX = mfma32(FX.m, FX.m, GX);
    GY = mfma32(FY.m, FY.m, GY);
}

// spill a pair's Grams + xty into LDS slices (m101 C-layout rows)
__device__ __forceinline__ void spill_pair(
    const f32x16& GX, const f32x16& GY, float ayX, float ayY,
    int r, int g, float* sX, float* sY)
{
    #pragma unroll
    for (int reg = 0; reg < 16; ++reg) {
        const int row = (reg & 3) + 8 * (reg >> 2) + 4 * g;
        sX[row * AW + r] = GX[reg];
        sY[row * AW + r] = GY[reg];
    }
    if (g == 0) sX[r * AW + 32] = ayX;
    else        sY[r * AW + 32] = ayY;
}

// ---- merged Gauss-Jordan round K (swizzle broadcast — r15 form) ----
template <int K>
__device__ __forceinline__ void gj_round(float (&A)[33], float& dinv, int r) {
    float piv = swz_f<(K << 5)>(A[K]);
    float ip = __builtin_amdgcn_rcpf(piv);
    const bool isk = (r == K);
    float fmul = isk ? 0.f : A[K] * ip;
    dinv = isk ? ip : dinv;
    #pragma unroll
    for (int m = K + 1; m < 33; ++m) {
        float pk = swz_f<(K << 5)>(A[m]);
        A[m] = fmaf(-fmul, pk, A[m]);
    }
}

template <int K, int END>
struct GJR {
    static __device__ __forceinline__ void run(float (&A)[33], float& dinv, int r) {
        gj_round<K>(A, dinv, r);
        GJR<K + 1, END>::run(A, dinv, r);
    }
};
template <int END>
struct GJR<END, END> {
    static __device__ __forceinline__ void run(float (&)[33], float&, int) {}
};

// One wave per FOUR tokens; pipelined: Gram(CD) chunks ∥ solve(AB) rounds.
__global__ __launch_bounds__(64, 4) void feat_kernel(
    const float* __restrict__ x,       // [B,T,32]
    const float* __restrict__ latent,  // [B,T,128]
    const float* __restrict__ kern,    // [32,128]
    const float* __restrict__ bias,    // [32,128]
    const float* __restrict__ beta,    // [T]
    float* __restrict__ out,           // mode0: ws[B,T,128] ; mode1: out[B,128]
    int mode)
{
    __shared__ __align__(16) char smem[2 * SLICE];
    const int lane = threadIdx.x;
    const int bt0  = blockIdx.x * 4;

    const int g = lane >> 5;
    const int r = lane & 31;

    float* s0 = reinterpret_cast<float*>(smem);
    float* s1 = reinterpret_cast<float*>(smem + SLICE);

    const float4* kern4 = reinterpret_cast<const float4*>(kern);
    const float4* bias4 = reinterpret_cast<const float4*>(bias);
    const float4* lat4  = reinterpret_cast<const float4*>(latent);
    const float4* latA4 = lat4 + (size_t)(bt0 + 0) * 32;
    const float4* latB4 = lat4 + (size_t)(bt0 + 1) * 32;
    const float4* latC4 = lat4 + (size_t)(bt0 + 2) * 32;
    const float4* latD4 = lat4 + (size_t)(bt0 + 3) * 32;

    const float xA = x[(size_t)(bt0 + 0) * DF + r];
    const float xB = x[(size_t)(bt0 + 1) * DF + r];
    const float xC = x[(size_t)(bt0 + 2) * DF + r];
    const float xD = x[(size_t)(bt0 + 3) * DF + r];

    // ---- phase 1: Gram(AB) full, spill ----
    {
        f32x16 GA, GB;
        #pragma unroll
        for (int i = 0; i < 16; ++i) { GA[i] = 0.f; GB[i] = 0.f; }
        v2f ayA2 = {0.f, 0.f}, ayB2 = {0.f, 0.f};
        #pragma unroll
        for (int ks = 0; ks < 8; ++ks)
            gram_ks(ks, kern4, bias4, latA4, latB4, xA, xB, r, g, GA, GB, ayA2, ayB2);
        float ayA = ayA2[0] + ayA2[1];
        float ayB = ayB2[0] + ayB2[1];
        ayA += __shfl_xor(ayA, 32);
        ayB += __shfl_xor(ayB, 32);
        spill_pair(GA, GB, ayA, ayB, r, g, s0, s1);
    }
    WAVE_SYNC();

    // ---- load AB rows ----
    float Aab[33];
    {
        const float* Amy = g ? s1 : s0;
        #pragma unroll
        for (int m = 0; m < 16; ++m) {
            v2f t = *reinterpret_cast<const v2f*>(&Amy[r * AW + 2 * m]);
            Aab[2 * m]     = t[0];
            Aab[2 * m + 1] = t[1];
        }
        Aab[32] = Amy[r * AW + 32];
    }

    // ---- phase 2: Gram(CD) chunks interleaved with solve(AB) rounds ----
    f32x16 GC, GD;
    #pragma unroll
    for (int i = 0; i < 16; ++i) { GC[i] = 0.f; GD[i] = 0.f; }
    v2f ayC2 = {0.f, 0.f}, ayD2 = {0.f, 0.f};
    float dab = 0.f;

    gram_ks(0, kern4, bias4, latC4, latD4, xC, xD, r, g, GC, GD, ayC2, ayD2);
    gram_ks(1, kern4, bias4, latC4, latD4, xC, xD, r, g, GC, GD, ayC2, ayD2);
    GJR<0, 8>::run(Aab, dab, r);
    gram_ks(2, kern4, bias4, latC4, latD4, xC, xD, r, g, GC, GD, ayC2, ayD2);
    gram_ks(3, kern4, bias4, latC4, latD4, xC, xD, r, g, GC, GD, ayC2, ayD2);
    GJR<8, 16>::run(Aab, dab, r);
    gram_ks(4, kern4, bias4, latC4, latD4, xC, xD, r, g, GC, GD, ayC2, ayD2);
    gram_ks(5, kern4, bias4, latC4, latD4, xC, xD, r, g, GC, GD, ayC2, ayD2);
    GJR<16, 24>::run(Aab, dab, r);
    gram_ks(6, kern4, bias4, latC4, latD4, xC, xD, r, g, GC, GD, ayC2, ayD2);
    gram_ks(7, kern4, bias4, latC4, latD4, xC, xD, r, g, GC, GD, ayC2, ayD2);
    GJR<24, 32>::run(Aab, dab, r);
    const float sab = Aab[32] * dab;   // lane g*32+r: s of token (A if g==0 else B)[r]

    // ---- spill CD (slices dead: AB rows already in regs; swizzles don't touch LDS) ----
    {
        float ayC = ayC2[0] + ayC2[1];
        float ayD = ayD2[0] + ayD2[1];
        ayC += __shfl_xor(ayC, 32);
        ayD += __shfl_xor(ayD, 32);
        spill_pair(GC, GD, ayC, ayD, r, g, s0, s1);
    }
    WAVE_SYNC();

    // ---- load CD rows, solve ----
    float Acd[33];
    {
        const float* Amy = g ? s1 : s0;
        #pragma unroll
        for (int m = 0; m < 16; ++m) {
            v2f t = *reinterpret_cast<const v2f*>(&Amy[r * AW + 2 * m]);
            Acd[2 * m]     = t[0];
            Acd[2 * m + 1] = t[1];
        }
        Acd[32] = Amy[r * AW + 32];
    }
    float dcd = 0.f;
    GJR<0, 32>::run(Acd, dcd, r);
    const float scd = Acd[32] * dcd;

    // ---- o_hat all 4 tokens: each K/Bv load shared 4 ways ----
    {
        v2f oA01 = {0.f,0.f}, oA23 = {0.f,0.f}, oB01 = {0.f,0.f}, oB23 = {0.f,0.f};
        v2f oC01 = {0.f,0.f}, oC23 = {0.f,0.f}, oD01 = {0.f,0.f}, oD23 = {0.f,0.f};
        #pragma unroll
        for (int dd = 0; dd < 16; ++dd) {
            int d = g * 16 + dd;
            float4 K  = kern4[d * 32 + r];
            float4 Bv = bias4[d * 32 + r];
            v2f K01 = {K.x, K.y},  K23 = {K.z, K.w};
            v2f Bv01 = {Bv.x, Bv.y}, Bv23 = {Bv.z, Bv.w};
            float xvA = __shfl(xA, d), xvB = __shfl(xB, d);
            float xvC = __shfl(xC, d), xvD = __shfl(xD, d);
            float sA = __shfl(sab, d),      sB = __shfl(sab, 32 + d);
            float sC = __shfl(scd, d),      sD = __shfl(scd, 32 + d);
            v2f t01, t23;
            v2f xv2, sv2;
            xv2 = (v2f){xvA, xvA}; sv2 = (v2f){sA, sA};
            t01 = pk_fma(xv2, K01, Bv01); t23 = pk_fma(xv2, K23, Bv23);
            t01[0] = fmaxf(t01[0], 0.f); t01[1] = fmaxf(t01[1], 0.f);
            t23[0] = fmaxf(t23[0], 0.f); t23[1] = fmaxf(t23[1], 0.f);
            oA01 = pk_fma(sv2, t01, oA01); oA23 = pk_fma(sv2, t23, oA23);
            xv2 = (v2f){xvB, xvB}; sv2 = (v2f){sB, sB};
            t01 = pk_fma(xv2, K01, Bv01); t23 = pk_fma(xv2, K23, Bv23);
            t01[0] = fmaxf(t01[0], 0.f); t01[1] = fmaxf(t01[1], 0.f);
            t23[0] = fmaxf(t23[0], 0.f); t23[1] = fmaxf(t23[1], 0.f);
            oB01 = pk_fma(sv2, t01, oB01); oB23 = pk_fma(sv2, t23, oB23);
            xv2 = (v2f){xvC, xvC}; sv2 = (v2f){sC, sC};
            t01 = pk_fma(xv2, K01, Bv01); t23 = pk_fma(xv2, K23, Bv23);
            t01[0] = fmaxf(t01[0], 0.f); t01[1] = fmaxf(t01[1], 0.f);
            t23[0] = fmaxf(t23[0], 0.f); t23[1] = fmaxf(t23[1], 0.f);
            oC01 = pk_fma(sv2, t01, oC01); oC23 = pk_fma(sv2, t23, oC23);
            xv2 = (v2f){xvD, xvD}; sv2 = (v2f){sD, sD};
            t01 = pk_fma(xv2, K01, Bv01); t23 = pk_fma(xv2, K23, Bv23);
            t01[0] = fmaxf(t01[0], 0.f); t01[1] = fmaxf(t01[1], 0.f);
            t23[0] = fmaxf(t23[0], 0.f); t23[1] = fmaxf(t23[1], 0.f);
            oD01 = pk_fma(sv2, t01, oD01); oD23 = pk_fma(sv2, t23, oD23);
        }
        float4 oA = make_float4(oA01[0], oA01[1], oA23[0], oA23[1]);
        float4 oB = make_float4(oB01[0], oB01[1], oB23[0], oB23[1]);
        float4 oC = make_float4(oC01[0], oC01[1], oC23[0], oC23[1]);
        float4 oD = make_float4(oD01[0], oD01[1], oD23[0], oD23[1]);
        oA.x += __shfl_xor(oA.x, 32); oA.y += __shfl_xor(oA.y, 32);
        oA.z += __shfl_xor(oA.z, 32); oA.w += __shfl_xor(oA.w, 32);
        oB.x += __shfl_xor(oB.x, 32); oB.y += __shfl_xor(oB.y, 32);
        oB.z += __shfl_xor(oB.z, 32); oB.w += __shfl_xor(oB.w, 32);
        oC.x += __shfl_xor(oC.x, 32); oC.y += __shfl_xor(oC.y, 32);
        oC.z += __shfl_xor(oC.z, 32); oC.w += __shfl_xor(oC.w, 32);
        oD.x += __shfl_xor(oD.x, 32); oD.y += __shfl_xor(oD.y, 32);
        oD.z += __shfl_xor(oD.z, 32); oD.w += __shfl_xor(oD.w, 32);

        if (mode == 0) {
            if (g == 0) {
                reinterpret_cast<float4*>(out)[(size_t)(bt0 + 0) * 32 + r] = oA;
                reinterpret_cast<float4*>(out)[(size_t)(bt0 + 2) * 32 + r] = oC;
            } else {
                reinterpret_cast<float4*>(out)[(size_t)(bt0 + 1) * 32 + r] = oB;
                reinterpret_cast<float4*>(out)[(size_t)(bt0 + 3) * 32 + r] = oD;
            }
        } else {
            float v = fabsf(beta[lane]) + fabsf(beta[lane + 64]) +
                      fabsf(beta[lane + 128]) + fabsf(beta[lane + 192]);
            #pragma unroll
            for (int off = 32; off > 0; off >>= 1) v += __shfl_down(v, off);
            float S = __shfl(v, 0);
            const int b = bt0 >> 8;
            float* op = &out[(size_t)b * L_ + 4 * r];
            if (g == 0) {
                float wA = fabsf(beta[(bt0 + 0) & (T_ - 1)]) / S;
                float wC = fabsf(beta[(bt0 + 2) & (T_ - 1)]) / S;
                atomicAdd(op + 0, oA.x * wA + oC.x * wC);
                atomicAdd(op + 1, oA.y * wA + oC.y * wC);
                atomicAdd(op + 2, oA.z * wA + oC.z * wC);
                atomicAdd(op + 3, oA.w * wA + oC.w * wC);
            } else {
                float wB = fabsf(beta[(bt0 + 1) & (T_ - 1)]) / S;
                float wD = fabsf(beta[(bt0 + 3) & (T_ - 1)]) / S;
                atomicAdd(op + 0, oB.x * wB + oD.x * wD);
                atomicAdd(op + 1, oB.y * wB + oD.y * wD);
                atomicAdd(op + 2, oB.z * wB + oD.z * wD);
                atomicAdd(op + 3, oB.w * wB + oD.w * wD);
            }
        }
    }
}

__global__ __launch_bounds__(256) void reduce_kernel(
    const float* __restrict__ ws,     // [B,T,128] o_hat (unscaled)
    const float* __restrict__ beta,   // [T]
    float* __restrict__ out)          // [B,128]
{
    __shared__ float wsh[T_];
    __shared__ __align__(16) float4 par[8][32];
    __shared__ float red[4];
    const int b = blockIdx.x, tid = threadIdx.x;

    float bv = fabsf(beta[tid]);
    wsh[tid] = bv;
    float v = bv;
    #pragma unroll
    for (int o = 32; o > 0; o >>= 1) v += __shfl_down(v, o);
    if ((tid & 63) == 0) red[tid >> 6] = v;
    __syncthreads();
    const float S = red[0] + red[1] + red[2] + red[3];

    const int c = tid & 31, gg = tid >> 5;
    const float4* ws4 = reinterpret_cast<const float4*>(ws);
    float4 a = make_float4(0.f, 0.f, 0.f, 0.f);
    #pragma unroll 4
    for (int tt = 0; tt < 32; ++tt) {
        int t = gg * 32 + tt;
        float w = wsh[t];
        float4 u = ws4[((size_t)b * T_ + t) * 32 + c];
        a.x = fmaf(u.x, w, a.x);
        a.y = fmaf(u.y, w, a.y);
        a.z = fmaf(u.z, w, a.z);
        a.w = fmaf(u.w, w, a.w);
    }
    par[gg][c] = a;
    __syncthreads();
    if (tid < 32) {
        float4 s = par[0][tid];
        #pragma unroll
        for (int p = 1; p < 8; ++p) {
            float4 u = par[p][tid];
            s.x += u.x; s.y += u.y; s.z += u.z; s.w += u.w;
        }
        float inv = 1.0f / S;
        s.x *= inv; s.y *= inv; s.z *= inv; s.w *= inv;
        reinterpret_cast<float4*>(out)[b * 32 + tid] = s;
    }
}

extern "C" void kernel_launch(void* const* d_in, const int* in_sizes, int n_in,
                              void* d_out, int out_size, void* d_ws, size_t ws_size,
                              hipStream_t stream) {
    const float* x      = (const float*)d_in[0];
    const float* latent = (const float*)d_in[1];
    const float* kern   = (const float*)d_in[2];
    const float* bias   = (const float*)d_in[3];
    const float* beta   = (const float*)d_in[4];
    float* out = (float*)d_out;

    const size_t need = (size_t)B_ * T_ * L_ * sizeof(float);
    if (ws_size >= need) {
        float* ws = (float*)d_ws;
        feat_kernel<<<(B_ * T_) / 4, 64, 0, stream>>>(x, latent, kern, bias, beta, ws, 0);
        reduce_kernel<<<B_, 256, 0, stream>>>(ws, beta, out);
    } else {
        (void)hipMemsetAsync(d_out, 0, (size_t)out_size * sizeof(float), stream);
        feat_kernel<<<(B_ * T_) / 4, 64, 0, stream>>>(x, latent, kern, bias, beta, out, 1);
    }
}

// Round 18
// 73.538 us; speedup vs baseline: 1.1603x; 1.0639x over previous
//
#include <hip/hip_runtime.h>
#include <stdint.h>

#define B_ 64
#define T_ 256
#define DF 32
#define L_ 128
#define AW 34      // solve-matrix row stride in floats
#define SLICE 4352 // one token's solve matrix: 32*34*4

typedef float  v2f    __attribute__((ext_vector_type(2)));
typedef float  f32x16 __attribute__((ext_vector_type(16)));
typedef short  bf16x8 __attribute__((ext_vector_type(8)));

// wave-private barrier: drain LDS ops; sched_barrier stops hoisting (rule #18)
#define WAVE_SYNC() do { asm volatile("s_waitcnt lgkmcnt(0)" ::: "memory"); \
                         __builtin_amdgcn_sched_barrier(0); } while (0)

// ds_swizzle with compile-time immediate (builtin requires an ICE argument)
template <int IMM>
__device__ __forceinline__ float swz_f(float v) {
    return __builtin_bit_cast(float, __builtin_amdgcn_ds_swizzle(
        __builtin_bit_cast(int, v), IMM));
}
__device__ __forceinline__ float readlane_f(float v, int l) {
    return __builtin_bit_cast(float, __builtin_amdgcn_readlane(__builtin_bit_cast(int, v), l));
}
__device__ __forceinline__ v2f pk_fma(v2f a, v2f b, v2f c) {
    v2f d;
    asm("v_pk_fma_f32 %0, %1, %2, %3" : "=v"(d) : "v"(a), "v"(b), "v"(c));
    return d;
}
__device__ __forceinline__ uint32_t cvt_pk_bf16(float a, float b) {
    uint32_t r;
    asm("v_cvt_pk_bf16_f32 %0, %1, %2" : "=v"(r) : "v"(a), "v"(b));
    return r;   // lo16 = bf16(a), hi16 = bf16(b)
}
__device__ __forceinline__ float lo_f(uint32_t p) { return __builtin_bit_cast(float, p << 16); }
__device__ __forceinline__ float hi_f(uint32_t p) { return __builtin_bit_cast(float, p & 0xFFFF0000u); }

struct frag2m { bf16x8 h, m; };
union U8 { uint32_t u[4]; bf16x8 v; };

// 2-way bf16 split of 8 f32 values (four v2f): f ~= h + m, residual ~2^-18
__device__ __forceinline__ frag2m split2(v2f p0, v2f p1, v2f p2, v2f p3) {
    uint32_t h0 = cvt_pk_bf16(p0[0], p0[1]), h1 = cvt_pk_bf16(p1[0], p1[1]);
    uint32_t h2 = cvt_pk_bf16(p2[0], p2[1]), h3 = cvt_pk_bf16(p3[0], p3[1]);
    float e0 = p0[0] - lo_f(h0), e1 = p0[1] - hi_f(h0);
    float e2 = p1[0] - lo_f(h1), e3 = p1[1] - hi_f(h1);
    float e4 = p2[0] - lo_f(h2), e5 = p2[1] - hi_f(h2);
    float e6 = p3[0] - lo_f(h3), e7 = p3[1] - hi_f(h3);
    uint32_t m0 = cvt_pk_bf16(e0, e1), m1 = cvt_pk_bf16(e2, e3);
    uint32_t m2 = cvt_pk_bf16(e4, e5), m3 = cvt_pk_bf16(e6, e7);
    U8 H, M;
    H.u[0] = h0; H.u[1] = h1; H.u[2] = h2; H.u[3] = h3;
    M.u[0] = m0; M.u[1] = m1; M.u[2] = m2; M.u[3] = m3;
    frag2m r; r.h = H.v; r.m = M.v; return r;
}

__device__ __forceinline__ f32x16 mfma32(bf16x8 a, bf16x8 b, f32x16 c) {
    return __builtin_amdgcn_mfma_f32_32x32x16_bf16(a, b, c, 0, 0, 0);
}

// ---- merged Gauss-Jordan round K, HYBRID broadcast ----
// lane g*32+r holds FULL row r (33 floats) of token g.
// Even-offset columns: ds_swizzle (DS pipe, 1 op serves both tokens).
// Odd-offset columns: 2x v_readlane + 2 half-masked fma (VALU pipe).
// Splits the broadcast load across the CU's two independent pipes.
template <int K>
__device__ __forceinline__ void gj_round(float (&A)[33], float& dinv, int r, int g) {
    float piv = swz_f<(K << 5)>(A[K]);               // my token's A[K][K]
    float ip = __builtin_amdgcn_rcpf(piv);           // ~1 ulp native rcp
    const bool isk = (r == K);
    float fmul = isk ? 0.f : A[K] * ip;              // my row's col-K value
    dinv = isk ? ip : dinv;                          // capture my diagonal reciprocal
    float fA = g ? 0.f : fmul;                       // half-masked multipliers
    float fB = g ? fmul : 0.f;
    #pragma unroll
    for (int m = K + 1; m < 33; ++m) {
        if (((m - K) & 1) == 0) {
            float pk = swz_f<(K << 5)>(A[m]);        // DS-pipe broadcast
            A[m] = fmaf(-fmul, pk, A[m]);
        } else {
            float pkA = readlane_f(A[m], K);         // VALU-pipe broadcast
            float pkB = readlane_f(A[m], 32 + K);
            A[m] = fmaf(-fA, pkA, A[m]);
            A[m] = fmaf(-fB, pkB, A[m]);
        }
    }
}

template <int K>
struct GJ {
    static __device__ __forceinline__ void run(float (&A)[33], float& dinv, int r, int g) {
        gj_round<K>(A, dinv, r, g);
        GJ<K + 1>::run(A, dinv, r, g);
    }
};
template <>
struct GJ<32> {
    static __device__ __forceinline__ void run(float (&)[33], float&, int, int) {}
};

// 256-thread blocks = 4 independent waves (no __syncthreads); each wave: 2 tokens.
__global__ __launch_bounds__(256, 4) void feat_kernel(
    const float* __restrict__ x,       // [B,T,32]
    const float* __restrict__ latent,  // [B,T,128]
    const float* __restrict__ kern,    // [32,128]
    const float* __restrict__ bias,    // [32,128]
    const float* __restrict__ beta,    // [T]
    float* __restrict__ out,           // mode0: ws[B,T,128] ; mode1: out[B,128]
    int mode)
{
    __shared__ __align__(16) char smem[8 * SLICE];
    const int tid  = threadIdx.x;
    const int wid  = tid >> 6;         // wave within block (0..3)
    const int lane = tid & 63;
    const int btA  = blockIdx.x * 8 + wid * 2;
    const int btB  = btA + 1;

    const int g = lane >> 5;
    const int r = lane & 31;

    float* AsA = reinterpret_cast<float*>(smem + (wid * 2 + 0) * SLICE);
    float* AsB = reinterpret_cast<float*>(smem + (wid * 2 + 1) * SLICE);

    const float4* kern4 = reinterpret_cast<const float4*>(kern);
    const float4* bias4 = reinterpret_cast<const float4*>(bias);
    const float4* latA4 = reinterpret_cast<const float4*>(latent) + (size_t)btA * 32;
    const float4* latB4 = reinterpret_cast<const float4*>(latent) + (size_t)btB * 32;

    const float xA = x[(size_t)btA * DF + r];   // x_A[r] in every lane (both halves)
    const float xB = x[(size_t)btB * DF + r];
    const v2f xA2 = {xA, xA}, xB2 = {xB, xB};

    f32x16 GA, GB;
    #pragma unroll
    for (int i = 0; i < 16; ++i) { GA[i] = 0.f; GB[i] = 0.f; }
    v2f ayA2 = {0.f, 0.f}, ayB2 = {0.f, 0.f};

    // ---- 8 k-steps of 16: shared K/B loads, both tokens' frags, 8 MFMA/ks ----
    #pragma unroll 2
    for (int ks = 0; ks < 8; ++ks) {
        const int idx = r * 32 + ks * 4 + g * 2;   // float4 index; k = ks*16 + g*8
        float4 Ka = kern4[idx],  Kb = kern4[idx + 1];
        float4 Ba = bias4[idx],  Bb = bias4[idx + 1];
        v2f K0 = {Ka.x, Ka.y}, K1 = {Ka.z, Ka.w};
        v2f K2 = {Kb.x, Kb.y}, K3 = {Kb.z, Kb.w};
        v2f B0 = {Ba.x, Ba.y}, B1 = {Ba.z, Ba.w};
        v2f B2 = {Bb.x, Bb.y}, B3 = {Bb.z, Bb.w};

        // token A features (pk fma + scalar relu)
        v2f a0 = pk_fma(xA2, K0, B0), a1 = pk_fma(xA2, K1, B1);
        v2f a2 = pk_fma(xA2, K2, B2), a3 = pk_fma(xA2, K3, B3);
        a0[0] = fmaxf(a0[0], 0.f); a0[1] = fmaxf(a0[1], 0.f);
        a1[0] = fmaxf(a1[0], 0.f); a1[1] = fmaxf(a1[1], 0.f);
        a2[0] = fmaxf(a2[0], 0.f); a2[1] = fmaxf(a2[1], 0.f);
        a3[0] = fmaxf(a3[0], 0.f); a3[1] = fmaxf(a3[1], 0.f);
        // token B features
        v2f b0 = pk_fma(xB2, K0, B0), b1 = pk_fma(xB2, K1, B1);
        v2f b2 = pk_fma(xB2, K2, B2), b3 = pk_fma(xB2, K3, B3);
        b0[0] = fmaxf(b0[0], 0.f); b0[1] = fmaxf(b0[1], 0.f);
        b1[0] = fmaxf(b1[0], 0.f); b1[1] = fmaxf(b1[1], 0.f);
        b2[0] = fmaxf(b2[0], 0.f); b2[1] = fmaxf(b2[1], 0.f);
        b3[0] = fmaxf(b3[0], 0.f); b3[1] = fmaxf(b3[1], 0.f);

        // xty partials (pk f32, exact)
        float4 laA = latA4[ks * 4 + g * 2], lbA = latA4[ks * 4 + g * 2 + 1];
        float4 laB = latB4[ks * 4 + g * 2], lbB = latB4[ks * 4 + g * 2 + 1];
        v2f lA0 = {laA.x, laA.y}, lA1 = {laA.z, laA.w};
        v2f lA2 = {lbA.x, lbA.y}, lA3 = {lbA.z, lbA.w};
        v2f lB0 = {laB.x, laB.y}, lB1 = {laB.z, laB.w};
        v2f lB2 = {lbB.x, lbB.y}, lB3 = {lbB.z, lbB.w};
        ayA2 = pk_fma(a0, lA0, ayA2); ayA2 = pk_fma(a1, lA1, ayA2);
        ayA2 = pk_fma(a2, lA2, ayA2); ayA2 = pk_fma(a3, lA3, ayA2);
        ayB2 = pk_fma(b0, lB0, ayB2); ayB2 = pk_fma(b1, lB1, ayB2);
        ayB2 = pk_fma(b2, lB2, ayB2); ayB2 = pk_fma(b3, lB3, ayB2);

        frag2m FA = split2(a0, a1, a2, a3);
        frag2m FB = split2(b0, b1, b2, b3);
        // G += (h+m)(h+m)^T exactly: hh + hm + mh + mm  (residual ~2^-17 rel)
        GA = mfma32(FA.h, FA.h, GA);
        GB = mfma32(FB.h, FB.h, GB);
        GA = mfma32(FA.h, FA.m, GA);
        GB = mfma32(FB.h, FB.m, GB);
        GA = mfma32(FA.m, FA.h, GA);
        GB = mfma32(FB.m, FB.h, GB);
        GA = mfma32(FA.m, FA.m, GA);
        GB = mfma32(FB.m, FB.m, GB);
    }
    float ayA = ayA2[0] + ayA2[1];
    float ayB = ayB2[0] + ayB2[1];
    ayA += __shfl_xor(ayA, 32);   // full xty_A[r] in every lane
    ayB += __shfl_xor(ayB, 32);

    // ---- spill both Grams + xty into LDS (row-major, m101 C-layout) ----
    #pragma unroll
    for (int reg = 0; reg < 16; ++reg) {
        const int row = (reg & 3) + 8 * (reg >> 2) + 4 * g;
        AsA[row * AW + r] = GA[reg];
        AsB[row * AW + r] = GB[reg];
    }
    if (g == 0) AsA[r * AW + 32] = ayA;
    else        AsB[r * AW + 32] = ayB;
    WAVE_SYNC();

    // ---- reload: lane g*32+r <- FULL row r of token g ----
    float A[33];
    {
        const float* Amy = g ? AsB : AsA;
        #pragma unroll
        for (int m = 0; m < 16; ++m) {
            v2f t = *reinterpret_cast<const v2f*>(&Amy[r * AW + 2 * m]);
            A[2 * m]     = t[0];
            A[2 * m + 1] = t[1];
        }
        A[32] = Amy[r * AW + 32];
    }

    // ---- merged register Gauss-Jordan: hybrid DS/VALU broadcasts ----
    float dinv = 0.f;
    GJ<0>::run(A, dinv, r, g);
    const float s = A[32] * dinv;   // lane g*32+r: solution s_g[r]

    // ---- o_hat both tokens: shared K/Bv loads, f4-col = r, d split across halves ----
    {
        v2f oA01 = {0.f, 0.f}, oA23 = {0.f, 0.f};
        v2f oB01 = {0.f, 0.f}, oB23 = {0.f, 0.f};
        #pragma unroll
        for (int dd = 0; dd < 16; ++dd) {
            int d = g * 16 + dd;
            float4 K  = kern4[d * 32 + r];
            float4 Bv = bias4[d * 32 + r];
            v2f K01 = {K.x, K.y},  K23 = {K.z, K.w};
            v2f Bv01 = {Bv.x, Bv.y}, Bv23 = {Bv.z, Bv.w};
            float xvA = __shfl(xA, d);        // x_A[d]
            float xvB = __shfl(xB, d);
            v2f xvA2 = {xvA, xvA}, xvB2 = {xvB, xvB};
            float sA = __shfl(s, d);          // s_A[d] (from half 0)
            float sB = __shfl(s, 32 + d);     // s_B[d] (from half 1)
            v2f sA2 = {sA, sA}, sB2 = {sB, sB};
            v2f f01 = pk_fma(xvA2, K01, Bv01);
            v2f f23 = pk_fma(xvA2, K23, Bv23);
            f01[0] = fmaxf(f01[0], 0.f); f01[1] = fmaxf(f01[1], 0.f);
            f23[0] = fmaxf(f23[0], 0.f); f23[1] = fmaxf(f23[1], 0.f);
            oA01 = pk_fma(sA2, f01, oA01);
            oA23 = pk_fma(sA2, f23, oA23);
            f01 = pk_fma(xvB2, K01, Bv01);
            f23 = pk_fma(xvB2, K23, Bv23);
            f01[0] = fmaxf(f01[0], 0.f); f01[1] = fmaxf(f01[1], 0.f);
            f23[0] = fmaxf(f23[0], 0.f); f23[1] = fmaxf(f23[1], 0.f);
            oB01 = pk_fma(sB2, f01, oB01);
            oB23 = pk_fma(sB2, f23, oB23);
        }
        float4 oA = make_float4(oA01[0], oA01[1], oA23[0], oA23[1]);
        float4 oB = make_float4(oB01[0], oB01[1], oB23[0], oB23[1]);
        oA.x += __shfl_xor(oA.x, 32); oA.y += __shfl_xor(oA.y, 32);
        oA.z += __shfl_xor(oA.z, 32); oA.w += __shfl_xor(oA.w, 32);
        oB.x += __shfl_xor(oB.x, 32); oB.y += __shfl_xor(oB.y, 32);
        oB.z += __shfl_xor(oB.z, 32); oB.w += __shfl_xor(oB.w, 32);

        if (mode == 0) {
            if (g == 0) reinterpret_cast<float4*>(out)[(size_t)btA * 32 + r] = oA;
            else        reinterpret_cast<float4*>(out)[(size_t)btB * 32 + r] = oB;
        } else {
            float v = fabsf(beta[lane]) + fabsf(beta[lane + 64]) +
                      fabsf(beta[lane + 128]) + fabsf(beta[lane + 192]);
            #pragma unroll
            for (int off = 32; off > 0; off >>= 1) v += __shfl_down(v, off);
            float S = __shfl(v, 0);
            const int tA = btA & (T_ - 1), tB = btB & (T_ - 1);
            const int b  = btA >> 8;
            float* op = &out[(size_t)b * L_ + 4 * r];
            if (g == 0) {
                float w_t = fabsf(beta[tA]) / S;
                atomicAdd(op + 0, oA.x * w_t);
                atomicAdd(op + 1, oA.y * w_t);
                atomicAdd(op + 2, oA.z * w_t);
                atomicAdd(op + 3, oA.w * w_t);
            } else {
                float w_t = fabsf(beta[tB]) / S;
                atomicAdd(op + 0, oB.x * w_t);
                atomicAdd(op + 1, oB.y * w_t);
                atomicAdd(op + 2, oB.z * w_t);
                atomicAdd(op + 3, oB.w * w_t);
            }
        }
    }
}

__global__ __launch_bounds__(256) void reduce_kernel(
    const float* __restrict__ ws,     // [B,T,128] o_hat (unscaled)
    const float* __restrict__ beta,   // [T]
    float* __restrict__ out)          // [B,128]
{
    __shared__ float wsh[T_];
    __shared__ __align__(16) float4 par[8][32];
    __shared__ float red[4];
    const int b = blockIdx.x, tid = threadIdx.x;

    float bv = fabsf(beta[tid]);
    wsh[tid] = bv;
    float v = bv;
    #pragma unroll
    for (int o = 32; o > 0; o >>= 1) v += __shfl_down(v, o);
    if ((tid & 63) == 0) red[tid >> 6] = v;
    __syncthreads();
    const float S = red[0] + red[1] + red[2] + red[3];

    const int c = tid & 31, gg = tid >> 5;
    const float4* ws4 = reinterpret_cast<const float4*>(ws);
    float4 a = make_float4(0.f, 0.f, 0.f, 0.f);
    #pragma unroll 4
    for (int tt = 0; tt < 32; ++tt) {
        int t = gg * 32 + tt;
        float w = wsh[t];
        float4 u = ws4[((size_t)b * T_ + t) * 32 + c];
        a.x = fmaf(u.x, w, a.x);
        a.y = fmaf(u.y, w, a.y);
        a.z = fmaf(u.z, w, a.z);
        a.w = fmaf(u.w, w, a.w);
    }
    par[gg][c] = a;
    __syncthreads();
    if (tid < 32) {
        float4 s = par[0][tid];
        #pragma unroll
        for (int p = 1; p < 8; ++p) {
            float4 u = par[p][tid];
            s.x += u.x; s.y += u.y; s.z += u.z; s.w += u.w;
        }
        float inv = 1.0f / S;
        s.x *= inv; s.y *= inv; s.z *= inv; s.w *= inv;
        reinterpret_cast<float4*>(out)[b * 32 + tid] = s;
    }
}

extern "C" void kernel_launch(void* const* d_in, const int* in_sizes, int n_in,
                              void* d_out, int out_size, void* d_ws, size_t ws_size,
                              hipStream_t stream) {
    const float* x      = (const float*)d_in[0];
    const float* latent = (const float*)d_in[1];
    const float* kern   = (const float*)d_in[2];
    const float* bias   = (const float*)d_in[3];
    const float* beta   = (const float*)d_in[4];
    float* out = (float*)d_out;

    const size_t need = (size_t)B_ * T_ * L_ * sizeof(float);
    if (ws_size >= need) {
        float* ws = (float*)d_ws;
        feat_kernel<<<(B_ * T_) / 8, 256, 0, stream>>>(x, latent, kern, bias, beta, ws, 0);
        reduce_kernel<<<B_, 256, 0, stream>>>(ws, beta, out);
    } else {
        (void)hipMemsetAsync(d_out, 0, (size_t)out_size * sizeof(float), stream);
        feat_kernel<<<(B_ * T_) / 8, 256, 0, stream>>>(x, latent, kern, bias, beta, out, 1);
    }
}

// Round 19
// 67.789 us; speedup vs baseline: 1.2587x; 1.0848x over previous
//
#include <hip/hip_runtime.h>
#include <stdint.h>

#define B_ 64
#define T_ 256
#define DF 32
#define L_ 128
#define AW 34      // solve-matrix row stride in floats
#define SLICE 4352 // one token's solve matrix: 32*34*4

typedef float  v2f    __attribute__((ext_vector_type(2)));
typedef float  f32x16 __attribute__((ext_vector_type(16)));
typedef short  bf16x8 __attribute__((ext_vector_type(8)));

// wave-private barrier: drain LDS ops; sched_barrier stops hoisting (rule #18)
#define WAVE_SYNC() do { asm volatile("s_waitcnt lgkmcnt(0)" ::: "memory"); \
                         __builtin_amdgcn_sched_barrier(0); } while (0)

// ds_swizzle with compile-time immediate (builtin requires an ICE argument)
template <int IMM>
__device__ __forceinline__ float swz_f(float v) {
    return __builtin_bit_cast(float, __builtin_amdgcn_ds_swizzle(
        __builtin_bit_cast(int, v), IMM));
}
__device__ __forceinline__ v2f pk_fma(v2f a, v2f b, v2f c) {
    v2f d;
    asm("v_pk_fma_f32 %0, %1, %2, %3" : "=v"(d) : "v"(a), "v"(b), "v"(c));
    return d;
}
__device__ __forceinline__ uint32_t cvt_pk_bf16(float a, float b) {
    uint32_t r;
    asm("v_cvt_pk_bf16_f32 %0, %1, %2" : "=v"(r) : "v"(a), "v"(b));
    return r;   // lo16 = bf16(a), hi16 = bf16(b)
}
__device__ __forceinline__ float lo_f(uint32_t p) { return __builtin_bit_cast(float, p << 16); }
__device__ __forceinline__ float hi_f(uint32_t p) { return __builtin_bit_cast(float, p & 0xFFFF0000u); }

struct frag2m { bf16x8 h, m; };
union U8 { uint32_t u[4]; bf16x8 v; };

// 2-way bf16 split of 8 f32 values (four v2f): f ~= h + m, residual ~2^-18
__device__ __forceinline__ frag2m split2(v2f p0, v2f p1, v2f p2, v2f p3) {
    uint32_t h0 = cvt_pk_bf16(p0[0], p0[1]), h1 = cvt_pk_bf16(p1[0], p1[1]);
    uint32_t h2 = cvt_pk_bf16(p2[0], p2[1]), h3 = cvt_pk_bf16(p3[0], p3[1]);
    float e0 = p0[0] - lo_f(h0), e1 = p0[1] - hi_f(h0);
    float e2 = p1[0] - lo_f(h1), e3 = p1[1] - hi_f(h1);
    float e4 = p2[0] - lo_f(h2), e5 = p2[1] - hi_f(h2);
    float e6 = p3[0] - lo_f(h3), e7 = p3[1] - hi_f(h3);
    uint32_t m0 = cvt_pk_bf16(e0, e1), m1 = cvt_pk_bf16(e2, e3);
    uint32_t m2 = cvt_pk_bf16(e4, e5), m3 = cvt_pk_bf16(e6, e7);
    U8 H, M;
    H.u[0] = h0; H.u[1] = h1; H.u[2] = h2; H.u[3] = h3;
    M.u[0] = m0; M.u[1] = m1; M.u[2] = m2; M.u[3] = m3;
    frag2m r; r.h = H.v; r.m = M.v; return r;
}

__device__ __forceinline__ f32x16 mfma32(bf16x8 a, bf16x8 b, f32x16 c) {
    return __builtin_amdgcn_mfma_f32_32x32x16_bf16(a, b, c, 0, 0, 0);
}

// ---- merged Gauss-Jordan round K: half g solves token g's system ----
// lane g*32+r holds FULL row r (33 floats) of token g.
// ds_swizzle BitMode (or_mask=K) broadcasts lane K within each 32-lane group.
template <int K>
__device__ __forceinline__ void gj_round(float (&A)[33], float& dinv, int r) {
    float piv = swz_f<(K << 5)>(A[K]);               // my token's A[K][K]
    float ip = __builtin_amdgcn_rcpf(piv);           // ~1 ulp native rcp
    const bool isk = (r == K);
    float fmul = isk ? 0.f : A[K] * ip;              // my row's col-K value (in reg)
    dinv = isk ? ip : dinv;                          // capture my diagonal reciprocal
    #pragma unroll
    for (int m = K + 1; m < 33; ++m) {
        float pk = swz_f<(K << 5)>(A[m]);            // row K's col m, my token
        A[m] = fmaf(-fmul, pk, A[m]);
    }
}

template <int K>
struct GJ {
    static __device__ __forceinline__ void run(float (&A)[33], float& dinv, int r) {
        gj_round<K>(A, dinv, r);
        GJ<K + 1>::run(A, dinv, r);
    }
};
template <>
struct GJ<32> {
    static __device__ __forceinline__ void run(float (&)[33], float&, int) {}
};

// 256-thread blocks = 4 independent waves (no __syncthreads); each wave: 2 tokens.
__global__ __launch_bounds__(256, 4) void feat_kernel(
    const float* __restrict__ x,       // [B,T,32]
    const float* __restrict__ latent,  // [B,T,128]
    const float* __restrict__ kern,    // [32,128]
    const float* __restrict__ bias,    // [32,128]
    const float* __restrict__ beta,    // [T]
    float* __restrict__ out,           // mode0: ws[B,T,128] ; mode1: out[B,128]
    int mode)
{
    __shared__ __align__(16) char smem[8 * SLICE];
    const int tid  = threadIdx.x;
    const int wid  = tid >> 6;         // wave within block (0..3)
    const int lane = tid & 63;
    const int btA  = blockIdx.x * 8 + wid * 2;
    const int btB  = btA + 1;

    const int g = lane >> 5;
    const int r = lane & 31;

    float* AsA = reinterpret_cast<float*>(smem + (wid * 2 + 0) * SLICE);
    float* AsB = reinterpret_cast<float*>(smem + (wid * 2 + 1) * SLICE);

    const float4* kern4 = reinterpret_cast<const float4*>(kern);
    const float4* bias4 = reinterpret_cast<const float4*>(bias);
    const float4* latA4 = reinterpret_cast<const float4*>(latent) + (size_t)btA * 32;
    const float4* latB4 = reinterpret_cast<const float4*>(latent) + (size_t)btB * 32;

    const float xA = x[(size_t)btA * DF + r];   // x_A[r] in every lane (both halves)
    const float xB = x[(size_t)btB * DF + r];
    const v2f xA2 = {xA, xA}, xB2 = {xB, xB};

    f32x16 GA, GB;
    #pragma unroll
    for (int i = 0; i < 16; ++i) { GA[i] = 0.f; GB[i] = 0.f; }
    v2f ayA2 = {0.f, 0.f}, ayB2 = {0.f, 0.f};

    // ---- 8 k-steps of 16: shared K/B loads, both tokens' frags, 8 MFMA/ks ----
    #pragma unroll 2
    for (int ks = 0; ks < 8; ++ks) {
        const int idx = r * 32 + ks * 4 + g * 2;   // float4 index; k = ks*16 + g*8
        float4 Ka = kern4[idx],  Kb = kern4[idx + 1];
        float4 Ba = bias4[idx],  Bb = bias4[idx + 1];
        v2f K0 = {Ka.x, Ka.y}, K1 = {Ka.z, Ka.w};
        v2f K2 = {Kb.x, Kb.y}, K3 = {Kb.z, Kb.w};
        v2f B0 = {Ba.x, Ba.y}, B1 = {Ba.z, Ba.w};
        v2f B2 = {Bb.x, Bb.y}, B3 = {Bb.z, Bb.w};

        // token A features (pk fma + scalar relu)
        v2f a0 = pk_fma(xA2, K0, B0), a1 = pk_fma(xA2, K1, B1);
        v2f a2 = pk_fma(xA2, K2, B2), a3 = pk_fma(xA2, K3, B3);
        a0[0] = fmaxf(a0[0], 0.f); a0[1] = fmaxf(a0[1], 0.f);
        a1[0] = fmaxf(a1[0], 0.f); a1[1] = fmaxf(a1[1], 0.f);
        a2[0] = fmaxf(a2[0], 0.f); a2[1] = fmaxf(a2[1], 0.f);
        a3[0] = fmaxf(a3[0], 0.f); a3[1] = fmaxf(a3[1], 0.f);
        // token B features
        v2f b0 = pk_fma(xB2, K0, B0), b1 = pk_fma(xB2, K1, B1);
        v2f b2 = pk_fma(xB2, K2, B2), b3 = pk_fma(xB2, K3, B3);
        b0[0] = fmaxf(b0[0], 0.f); b0[1] = fmaxf(b0[1], 0.f);
        b1[0] = fmaxf(b1[0], 0.f); b1[1] = fmaxf(b1[1], 0.f);
        b2[0] = fmaxf(b2[0], 0.f); b2[1] = fmaxf(b2[1], 0.f);
        b3[0] = fmaxf(b3[0], 0.f); b3[1] = fmaxf(b3[1], 0.f);

        // xty partials (pk f32, exact)
        float4 laA = latA4[ks * 4 + g * 2], lbA = latA4[ks * 4 + g * 2 + 1];
        float4 laB = latB4[ks * 4 + g * 2], lbB = latB4[ks * 4 + g * 2 + 1];
        v2f lA0 = {laA.x, laA.y}, lA1 = {laA.z, laA.w};
        v2f lA2 = {lbA.x, lbA.y}, lA3 = {lbA.z, lbA.w};
        v2f lB0 = {laB.x, laB.y}, lB1 = {laB.z, laB.w};
        v2f lB2 = {lbB.x, lbB.y}, lB3 = {lbB.z, lbB.w};
        ayA2 = pk_fma(a0, lA0, ayA2); ayA2 = pk_fma(a1, lA1, ayA2);
        ayA2 = pk_fma(a2, lA2, ayA2); ayA2 = pk_fma(a3, lA3, ayA2);
        ayB2 = pk_fma(b0, lB0, ayB2); ayB2 = pk_fma(b1, lB1, ayB2);
        ayB2 = pk_fma(b2, lB2, ayB2); ayB2 = pk_fma(b3, lB3, ayB2);

        frag2m FA = split2(a0, a1, a2, a3);
        frag2m FB = split2(b0, b1, b2, b3);
        // G += (h+m)(h+m)^T exactly: hh + hm + mh + mm  (residual ~2^-17 rel)
        GA = mfma32(FA.h, FA.h, GA);
        GB = mfma32(FB.h, FB.h, GB);
        GA = mfma32(FA.h, FA.m, GA);
        GB = mfma32(FB.h, FB.m, GB);
        GA = mfma32(FA.m, FA.h, GA);
        GB = mfma32(FB.m, FB.h, GB);
        GA = mfma32(FA.m, FA.m, GA);
        GB = mfma32(FB.m, FB.m, GB);
    }
    float ayA = ayA2[0] + ayA2[1];
    float ayB = ayB2[0] + ayB2[1];
    ayA += __shfl_xor(ayA, 32);   // full xty_A[r] in every lane
    ayB += __shfl_xor(ayB, 32);

    // ---- spill both Grams + xty into LDS (row-major, m101 C-layout) ----
    #pragma unroll
    for (int reg = 0; reg < 16; ++reg) {
        const int row = (reg & 3) + 8 * (reg >> 2) + 4 * g;
        AsA[row * AW + r] = GA[reg];
        AsB[row * AW + r] = GB[reg];
    }
    if (g == 0) AsA[r * AW + 32] = ayA;
    else        AsB[r * AW + 32] = ayB;
    WAVE_SYNC();

    // ---- reload: lane g*32+r <- FULL row r of token g ----
    float A[33];
    {
        const float* Amy = g ? AsB : AsA;
        #pragma unroll
        for (int m = 0; m < 16; ++m) {
            v2f t = *reinterpret_cast<const v2f*>(&Amy[r * AW + 2 * m]);
            A[2 * m]     = t[0];
            A[2 * m + 1] = t[1];
        }
        A[32] = Amy[r * AW + 32];
    }

    // ---- merged register Gauss-Jordan: both tokens in lockstep, no barriers ----
    float dinv = 0.f;
    GJ<0>::run(A, dinv, r);
    const float s = A[32] * dinv;   // lane g*32+r: solution s_g[r]

    // ---- o_hat both tokens: shared K/Bv loads, f4-col = r, d split across halves ----
    {
        v2f oA01 = {0.f, 0.f}, oA23 = {0.f, 0.f};
        v2f oB01 = {0.f, 0.f}, oB23 = {0.f, 0.f};
        #pragma unroll
        for (int dd = 0; dd < 16; ++dd) {
            int d = g * 16 + dd;
            float4 K  = kern4[d * 32 + r];
            float4 Bv = bias4[d * 32 + r];
            v2f K01 = {K.x, K.y},  K23 = {K.z, K.w};
            v2f Bv01 = {Bv.x, Bv.y}, Bv23 = {Bv.z, Bv.w};
            float xvA = __shfl(xA, d);        // x_A[d]
            float xvB = __shfl(xB, d);
            v2f xvA2 = {xvA, xvA}, xvB2 = {xvB, xvB};
            float sA = __shfl(s, d);          // s_A[d] (from half 0)
            float sB = __shfl(s, 32 + d);     // s_B[d] (from half 1)
            v2f sA2 = {sA, sA}, sB2 = {sB, sB};
            v2f f01 = pk_fma(xvA2, K01, Bv01);
            v2f f23 = pk_fma(xvA2, K23, Bv23);
            f01[0] = fmaxf(f01[0], 0.f); f01[1] = fmaxf(f01[1], 0.f);
            f23[0] = fmaxf(f23[0], 0.f); f23[1] = fmaxf(f23[1], 0.f);
            oA01 = pk_fma(sA2, f01, oA01);
            oA23 = pk_fma(sA2, f23, oA23);
            f01 = pk_fma(xvB2, K01, Bv01);
            f23 = pk_fma(xvB2, K23, Bv23);
            f01[0] = fmaxf(f01[0], 0.f); f01[1] = fmaxf(f01[1], 0.f);
            f23[0] = fmaxf(f23[0], 0.f); f23[1] = fmaxf(f23[1], 0.f);
            oB01 = pk_fma(sB2, f01, oB01);
            oB23 = pk_fma(sB2, f23, oB23);
        }
        float4 oA = make_float4(oA01[0], oA01[1], oA23[0], oA23[1]);
        float4 oB = make_float4(oB01[0], oB01[1], oB23[0], oB23[1]);
        oA.x += __shfl_xor(oA.x, 32); oA.y += __shfl_xor(oA.y, 32);
        oA.z += __shfl_xor(oA.z, 32); oA.w += __shfl_xor(oA.w, 32);
        oB.x += __shfl_xor(oB.x, 32); oB.y += __shfl_xor(oB.y, 32);
        oB.z += __shfl_xor(oB.z, 32); oB.w += __shfl_xor(oB.w, 32);

        if (mode == 0) {
            if (g == 0) reinterpret_cast<float4*>(out)[(size_t)btA * 32 + r] = oA;
            else        reinterpret_cast<float4*>(out)[(size_t)btB * 32 + r] = oB;
        } else {
            float v = fabsf(beta[lane]) + fabsf(beta[lane + 64]) +
                      fabsf(beta[lane + 128]) + fabsf(beta[lane + 192]);
            #pragma unroll
            for (int off = 32; off > 0; off >>= 1) v += __shfl_down(v, off);
            float S = __shfl(v, 0);
            const int tA = btA & (T_ - 1), tB = btB & (T_ - 1);
            const int b  = btA >> 8;
            float* op = &out[(size_t)b * L_ + 4 * r];
            if (g == 0) {
                float w_t = fabsf(beta[tA]) / S;
                atomicAdd(op + 0, oA.x * w_t);
                atomicAdd(op + 1, oA.y * w_t);
                atomicAdd(op + 2, oA.z * w_t);
                atomicAdd(op + 3, oA.w * w_t);
            } else {
                float w_t = fabsf(beta[tB]) / S;
                atomicAdd(op + 0, oB.x * w_t);
                atomicAdd(op + 1, oB.y * w_t);
                atomicAdd(op + 2, oB.z * w_t);
                atomicAdd(op + 3, oB.w * w_t);
            }
        }
    }
}

__global__ __launch_bounds__(256) void reduce_kernel(
    const float* __restrict__ ws,     // [B,T,128] o_hat (unscaled)
    const float* __restrict__ beta,   // [T]
    float* __restrict__ out)          // [B,128]
{
    __shared__ float wsh[T_];
    __shared__ __align__(16) float4 par[8][32];
    __shared__ float red[4];
    const int b = blockIdx.x, tid = threadIdx.x;

    float bv = fabsf(beta[tid]);
    wsh[tid] = bv;
    float v = bv;
    #pragma unroll
    for (int o = 32; o > 0; o >>= 1) v += __shfl_down(v, o);
    if ((tid & 63) == 0) red[tid >> 6] = v;
    __syncthreads();
    const float S = red[0] + red[1] + red[2] + red[3];

    const int c = tid & 31, gg = tid >> 5;
    const float4* ws4 = reinterpret_cast<const float4*>(ws);
    float4 a = make_float4(0.f, 0.f, 0.f, 0.f);
    #pragma unroll 4
    for (int tt = 0; tt < 32; ++tt) {
        int t = gg * 32 + tt;
        float w = wsh[t];
        float4 u = ws4[((size_t)b * T_ + t) * 32 + c];
        a.x = fmaf(u.x, w, a.x);
        a.y = fmaf(u.y, w, a.y);
        a.z = fmaf(u.z, w, a.z);
        a.w = fmaf(u.w, w, a.w);
    }
    par[gg][c] = a;
    __syncthreads();
    if (tid < 32) {
        float4 s = par[0][tid];
        #pragma unroll
        for (int p = 1; p < 8; ++p) {
            float4 u = par[p][tid];
            s.x += u.x; s.y += u.y; s.z += u.z; s.w += u.w;
        }
        float inv = 1.0f / S;
        s.x *= inv; s.y *= inv; s.z *= inv; s.w *= inv;
        reinterpret_cast<float4*>(out)[b * 32 + tid] = s;
    }
}

extern "C" void kernel_launch(void* const* d_in, const int* in_sizes, int n_in,
                              void* d_out, int out_size, void* d_ws, size_t ws_size,
                              hipStream_t stream) {
    const float* x      = (const float*)d_in[0];
    const float* latent = (const float*)d_in[1];
    const float* kern   = (const float*)d_in[2];
    const float* bias   = (const float*)d_in[3];
    const float* beta   = (const float*)d_in[4];
    float* out = (float*)d_out;

    const size_t need = (size_t)B_ * T_ * L_ * sizeof(float);
    if (ws_size >= need) {
        float* ws = (float*)d_ws;
        feat_kernel<<<(B_ * T_) / 8, 256, 0, stream>>>(x, latent, kern, bias, beta, ws, 0);
        reduce_kernel<<<B_, 256, 0, stream>>>(ws, beta, out);
    } else {
        (void)hipMemsetAsync(d_out, 0, (size_t)out_size * sizeof(float), stream);
        feat_kernel<<<(B_ * T_) / 8, 256, 0, stream>>>(x, latent, kern, bias, beta, out, 1);
    }
}